// Round 1
// baseline (580.515 us; speedup 1.0000x reference)
//
#include <hip/hip_runtime.h>

namespace {

constexpr int NB_  = 2;
constexpr int TC_  = 1024;
constexpr int TP_  = 512;
constexpr int TT_  = 1536;   // TC + TP
constexpr int D_   = 128;
constexpr int H_   = 8;
constexpr int DK_  = 16;
constexpr int DFF_ = 512;
constexpr int L_   = 2;
constexpr int HOR_ = 96;
constexpr int NQ_  = 3;

// ---- output float offsets (return order: out, v_cond, v_pred, logs) ----
constexpr int OFF_OUT  = 0;
constexpr int OFF_VC   = NB_ * NQ_ * HOR_;            // 576
constexpr int OFF_VP   = OFF_VC + NB_ * TC_ * 8;      // 16960
constexpr int OFF_LOGS = OFF_VP + NB_ * TP_ * 4;      // 21056

// ---- workspace float offsets ----
constexpr int WS_XA  = 0;
constexpr int WS_XB  = WS_XA + NB_ * TT_ * D_;        // 393216
constexpr int WS_Q   = WS_XB + NB_ * TT_ * D_;
constexpr int WS_K   = WS_Q  + NB_ * TT_ * D_;
constexpr int WS_VC  = WS_K  + NB_ * TT_ * D_;
constexpr int WS_WVC = WS_VC + NB_ * TT_ * DK_;
constexpr int WS_BVC = WS_WVC + D_ * DK_;

// =======================================================================
// Selector: grouped causal conv (K=3) -> scores -> entmax15 over NV vars
// -> weighted sum. One block (128 threads) per (b, t).
// =======================================================================
template <int NV>
__global__ __launch_bounds__(128) void selector_kernel(
    const float* __restrict__ x, const float* __restrict__ cw,
    const float* __restrict__ cb, const float* __restrict__ sw,
    const float* __restrict__ sb, float* __restrict__ vout,
    float* __restrict__ xout, int Tsel, int row_off)
{
    const int blk = blockIdx.x;
    const int b = blk / Tsel;
    const int t = blk - b * Tsel;
    const int d = threadIdx.x;           // 0..127
    const int lane = d & 63, wave = d >> 6;

    __shared__ float wsum[2][NV];
    __shared__ float wls[NV];

    // load causal window x[b, t-2..t, v] (broadcast reads, L1-served)
    float xw[3 * NV];
    #pragma unroll
    for (int kk = 0; kk < 3; ++kk) {
        const int ts = t + kk - 2;
        #pragma unroll
        for (int v = 0; v < NV; ++v)
            xw[kk * NV + v] = (ts >= 0) ? x[((long)b * Tsel + ts) * NV + v] : 0.0f;
    }

    // conv output ls[v] for this d  (cross-correlation, no kernel flip)
    float ls[NV];
    #pragma unroll
    for (int v = 0; v < NV; ++v) {
        const float* cwp = cw + ((long)(v * D_ + d)) * 3;
        float a = cb[v * D_ + d];
        a = fmaf(xw[0 * NV + v], cwp[0], a);
        a = fmaf(xw[1 * NV + v], cwp[1], a);
        a = fmaf(xw[2 * NV + v], cwp[2], a);
        ls[v] = a;
    }

    // scores[v] = sum_d ls[v]*sw[d] + sb  (block reduction)
    {
        const float swd = sw[d];
        float p[NV];
        #pragma unroll
        for (int v = 0; v < NV; ++v) p[v] = ls[v] * swd;
        #pragma unroll
        for (int off = 32; off; off >>= 1) {
            #pragma unroll
            for (int v = 0; v < NV; ++v) p[v] += __shfl_xor(p[v], off);
        }
        if (lane == 0) {
            #pragma unroll
            for (int v = 0; v < NV; ++v) wsum[wave][v] = p[v];
        }
    }
    __syncthreads();

    if (d == 0) {
        // entmax15 over NV values: Newton on f(tau)=sum((u-tau)+^2)-1
        float u[NV];
        float m = -1e30f;
        #pragma unroll
        for (int v = 0; v < NV; ++v) {
            float s = wsum[0][v] + wsum[1][v] + sb[0];
            s = fminf(fmaxf(s, -10.0f), 10.0f);  // clip (noise term skipped: ~1e-4)
            u[v] = 0.5f * s;
            m = fmaxf(m, u[v]);
        }
        float tau = m - 1.0f;
        for (int it = 0; it < 40; ++it) {
            float S1 = 0.f, S2 = 0.f;
            #pragma unroll
            for (int v = 0; v < NV; ++v) {
                float dd = fmaxf(u[v] - tau, 0.f);
                S1 += dd; S2 = fmaf(dd, dd, S2);
            }
            const float f = S2 - 1.0f;
            if (f < 1e-7f) break;
            tau += f / (2.0f * S1);
        }
        #pragma unroll
        for (int v = 0; v < NV; ++v) {
            float dd = fmaxf(u[v] - tau, 0.f);
            wls[v] = dd * dd;
        }
    }
    __syncthreads();

    // weighted mix -> x row; weights -> v_out
    float acc = 0.f;
    #pragma unroll
    for (int v = 0; v < NV; ++v) acc = fmaf(ls[v], wls[v], acc);
    xout[((long)b * TT_ + row_off + t) * D_ + d] = acc;
    if (d < NV) vout[((long)b * Tsel + t) * NV + d] = wls[d];
}

// =======================================================================
// Per-layer prep: Wvc[i][dk] = mean_h Wv[i][h*16+dk], bvc = mean_h bv
// =======================================================================
__global__ __launch_bounds__(256) void prep_wvc_kernel(
    const float* __restrict__ Wv, const float* __restrict__ bv,
    float* __restrict__ wvc, float* __restrict__ bvc)
{
    const int tid = threadIdx.x;
    for (int idx = tid; idx < D_ * DK_; idx += 256) {
        const int i = idx >> 4, dk = idx & 15;
        float s = 0.f;
        #pragma unroll
        for (int hh = 0; hh < H_; ++hh) s += Wv[i * D_ + hh * DK_ + dk];
        wvc[idx] = s * 0.125f;
    }
    if (tid < DK_) {
        float s = 0.f;
        #pragma unroll
        for (int hh = 0; hh < H_; ++hh) s += bv[hh * DK_ + tid];
        bvc[tid] = s * 0.125f;
    }
}

// =======================================================================
// QKV: one block (128 threads) per row. q,k full; v folded to head-mean.
// =======================================================================
__global__ __launch_bounds__(128) void qkv_kernel(
    const float* __restrict__ x,
    const float* __restrict__ Wq, const float* __restrict__ bq,
    const float* __restrict__ Wk, const float* __restrict__ bk,
    const float* __restrict__ wvc, const float* __restrict__ bvc,
    float* __restrict__ q, float* __restrict__ k, float* __restrict__ vc)
{
    const int row = blockIdx.x;
    const int tid = threadIdx.x;
    __shared__ float xr[D_];
    xr[tid] = x[(long)row * D_ + tid];
    __syncthreads();

    float aq = bq[tid], ak = bk[tid];
    for (int i = 0; i < D_; ++i) {
        const float xv = xr[i];
        aq = fmaf(xv, Wq[i * D_ + tid], aq);
        ak = fmaf(xv, Wk[i * D_ + tid], ak);
    }
    q[(long)row * D_ + tid] = aq;
    k[(long)row * D_ + tid] = ak;

    if (tid < DK_) {
        float av = bvc[tid];
        for (int i = 0; i < D_; ++i) av = fmaf(xr[i], wvc[i * DK_ + tid], av);
        vc[(long)row * DK_ + tid] = av;
    }
}

// =======================================================================
// Attention: one block (256 threads) per (b, t).
//  scores(8 heads) -> entmax15 per head (Newton) -> w_avg -> logs,
//  out16 = w_avg @ v_comb -> @Wo + bo -> residual -> LN1 -> x1
// =======================================================================
__global__ __launch_bounds__(256) void attn_kernel(
    const float* __restrict__ q, const float* __restrict__ k,
    const float* __restrict__ vcomb, const float* __restrict__ xin,
    float* __restrict__ xout,
    const float* __restrict__ Wo, const float* __restrict__ bo,
    const float* __restrict__ lng, const float* __restrict__ lnb,
    float* __restrict__ logs)
{
    __shared__ float sc[H_][TT_ + 4];   // +4 pad: score-phase write conflicts
    __shared__ float qrow[D_];
    __shared__ float red[64];
    __shared__ float o16[DK_];
    __shared__ float yrow[D_];
    __shared__ float stat[2];

    const int blk = blockIdx.x;
    const int b = blk / TT_;
    const int t = blk - b * TT_;
    const int tid = threadIdx.x;
    const int lane = tid & 63, wave = tid >> 6;
    const long rowq  = (long)b * TT_ + t;
    const long bbase = (long)b * TT_;

    if (tid < D_) qrow[tid] = q[rowq * D_ + tid];
    __syncthreads();

    // ---- scores: u = (q.k / sqrt(16)) / 2 = dot * 0.125 ----
    {
        const int h  = tid & 7;
        const int sl = tid >> 3;   // 0..31
        const float4* q4 = (const float4*)(qrow + h * DK_);
        const float4 qa = q4[0], qb = q4[1], qc = q4[2], qd = q4[3];
        for (int s = sl; s <= t; s += 32) {
            const float4* kp = (const float4*)(k + (bbase + s) * D_ + h * DK_);
            const float4 ka = kp[0], kb = kp[1], kc = kp[2], kd = kp[3];
            float dot = qa.x*ka.x + qa.y*ka.y + qa.z*ka.z + qa.w*ka.w
                      + qb.x*kb.x + qb.y*kb.y + qb.z*kb.z + qb.w*kb.w
                      + qc.x*kc.x + qc.y*kc.y + qc.z*kc.z + qc.w*kc.w
                      + qd.x*kd.x + qd.y*kd.y + qd.z*kd.z + qd.w*kd.w;
            sc[h][s] = dot * 0.125f;
        }
    }
    __syncthreads();

    // ---- entmax15 per head: wave handles heads 2w, 2w+1 ----
    for (int hh = 0; hh < 2; ++hh) {
        const int hd = wave * 2 + hh;
        float m = -1e30f;
        for (int s = lane; s <= t; s += 64) m = fmaxf(m, sc[hd][s]);
        #pragma unroll
        for (int off = 32; off; off >>= 1) m = fmaxf(m, __shfl_xor(m, off));

        float tau = m - 1.0f;   // f(tau0) >= 0; Newton monotone from below
        for (int it = 0; it < 30; ++it) {
            float S1 = 0.f, S2 = 0.f;
            for (int s = lane; s <= t; s += 64) {
                const float d0 = fmaxf(sc[hd][s] - tau, 0.f);
                S1 += d0; S2 = fmaf(d0, d0, S2);
            }
            #pragma unroll
            for (int off = 32; off; off >>= 1) {
                S1 += __shfl_xor(S1, off);
                S2 += __shfl_xor(S2, off);
            }
            const float f = S2 - 1.0f;
            if (f < 1e-6f) break;            // wave-uniform
            tau += f / (2.0f * S1);
        }
        for (int s = lane; s <= t; s += 64) {
            const float d0 = fmaxf(sc[hd][s] - tau, 0.f);
            sc[hd][s] = d0 * d0;
        }
    }
    __syncthreads();

    // ---- w_avg -> logs; acc16 += w_avg * v_comb ----
    float4 A0 = make_float4(0,0,0,0), A1 = A0, A2 = A0, A3 = A0;
    float* lrow = logs + rowq * TT_;
    for (int s = tid; s < TT_; s += 256) {
        float wa = 0.f;
        if (s <= t) {
            wa = sc[0][s] + sc[1][s] + sc[2][s] + sc[3][s]
               + sc[4][s] + sc[5][s] + sc[6][s] + sc[7][s];
            wa *= 0.125f;
            const float4* vp = (const float4*)(vcomb + (bbase + s) * DK_);
            const float4 v0 = vp[0], v1 = vp[1], v2 = vp[2], v3 = vp[3];
            A0.x = fmaf(wa, v0.x, A0.x); A0.y = fmaf(wa, v0.y, A0.y);
            A0.z = fmaf(wa, v0.z, A0.z); A0.w = fmaf(wa, v0.w, A0.w);
            A1.x = fmaf(wa, v1.x, A1.x); A1.y = fmaf(wa, v1.y, A1.y);
            A1.z = fmaf(wa, v1.z, A1.z); A1.w = fmaf(wa, v1.w, A1.w);
            A2.x = fmaf(wa, v2.x, A2.x); A2.y = fmaf(wa, v2.y, A2.y);
            A2.z = fmaf(wa, v2.z, A2.z); A2.w = fmaf(wa, v2.w, A2.w);
            A3.x = fmaf(wa, v3.x, A3.x); A3.y = fmaf(wa, v3.y, A3.y);
            A3.z = fmaf(wa, v3.z, A3.z); A3.w = fmaf(wa, v3.w, A3.w);
        }
        lrow[s] = wa;   // zeros for masked tail (d_out is poisoned)
    }
    #pragma unroll
    for (int off = 32; off; off >>= 1) {
        A0.x += __shfl_xor(A0.x, off); A0.y += __shfl_xor(A0.y, off);
        A0.z += __shfl_xor(A0.z, off); A0.w += __shfl_xor(A0.w, off);
        A1.x += __shfl_xor(A1.x, off); A1.y += __shfl_xor(A1.y, off);
        A1.z += __shfl_xor(A1.z, off); A1.w += __shfl_xor(A1.w, off);
        A2.x += __shfl_xor(A2.x, off); A2.y += __shfl_xor(A2.y, off);
        A2.z += __shfl_xor(A2.z, off); A2.w += __shfl_xor(A2.w, off);
        A3.x += __shfl_xor(A3.x, off); A3.y += __shfl_xor(A3.y, off);
        A3.z += __shfl_xor(A3.z, off); A3.w += __shfl_xor(A3.w, off);
    }
    if (lane == 0) {
        float* r = red + wave * 16;
        r[0]=A0.x; r[1]=A0.y; r[2]=A0.z; r[3]=A0.w;
        r[4]=A1.x; r[5]=A1.y; r[6]=A1.z; r[7]=A1.w;
        r[8]=A2.x; r[9]=A2.y; r[10]=A2.z; r[11]=A2.w;
        r[12]=A3.x; r[13]=A3.y; r[14]=A3.z; r[15]=A3.w;
    }
    __syncthreads();
    if (tid < DK_) o16[tid] = red[tid] + red[16 + tid] + red[32 + tid] + red[48 + tid];
    __syncthreads();

    // ---- @Wo + bo, residual, LN1 ----
    float y = 0.f;
    if (tid < D_) {
        float a = bo[tid];
        #pragma unroll
        for (int j = 0; j < DK_; ++j) a = fmaf(o16[j], Wo[j * D_ + tid], a);
        y = xin[rowq * D_ + tid] + a;
        yrow[tid] = y;
    }
    __syncthreads();
    if (tid < 64) {
        float sm = yrow[tid] + yrow[tid + 64];
        #pragma unroll
        for (int off = 32; off; off >>= 1) sm += __shfl_xor(sm, off);
        if (tid == 0) stat[0] = sm * (1.0f / D_);
    }
    __syncthreads();
    if (tid < 64) {
        const float mean = stat[0];
        const float d0 = yrow[tid] - mean, d1 = yrow[tid + 64] - mean;
        float sv = fmaf(d0, d0, d1 * d1);
        #pragma unroll
        for (int off = 32; off; off >>= 1) sv += __shfl_xor(sv, off);
        if (tid == 0) stat[1] = sv * (1.0f / D_);
    }
    __syncthreads();
    if (tid < D_) {
        const float r = rsqrtf(stat[1] + 1e-5f);
        xout[rowq * D_ + tid] = (y - stat[0]) * r * lng[tid] + lnb[tid];
    }
}

// =======================================================================
// FFN + LN2: 8 rows per block (256 threads) to amortize weight reads.
// x_next = LN2(relu(x1@fw1+fb1)@fw2 + fb2 + x1)
// =======================================================================
__global__ __launch_bounds__(256) void ffn_kernel(
    const float* __restrict__ xin, float* __restrict__ xout,
    const float* __restrict__ fw1, const float* __restrict__ fb1,
    const float* __restrict__ fw2, const float* __restrict__ fb2,
    const float* __restrict__ g, const float* __restrict__ bta)
{
    __shared__ float xr[8][D_];
    __shared__ float hb[8][DFF_];
    __shared__ float yb[8][D_];

    const long row0 = (long)blockIdx.x * 8;
    const int tid = threadIdx.x;

    for (int i = tid; i < 8 * D_; i += 256) xr[i >> 7][i & 127] = xin[row0 * D_ + i];
    __syncthreads();

    // GEMM1 + relu
    for (int c = tid; c < DFF_; c += 256) {
        float acc[8] = {0,0,0,0,0,0,0,0};
        for (int i = 0; i < D_; ++i) {
            const float wv = fw1[i * DFF_ + c];
            #pragma unroll
            for (int r = 0; r < 8; ++r) acc[r] = fmaf(xr[r][i], wv, acc[r]);
        }
        const float bb = fb1[c];
        #pragma unroll
        for (int r = 0; r < 8; ++r) hb[r][c] = fmaxf(acc[r] + bb, 0.f);
    }
    __syncthreads();

    // GEMM2 + bias + residual
    {
        const int d = tid & 127;
        const int r0 = (tid >> 7) * 4;
        float a0 = 0.f, a1 = 0.f, a2 = 0.f, a3 = 0.f;
        for (int j = 0; j < DFF_; ++j) {
            const float wv = fw2[j * D_ + d];
            a0 = fmaf(hb[r0 + 0][j], wv, a0);
            a1 = fmaf(hb[r0 + 1][j], wv, a1);
            a2 = fmaf(hb[r0 + 2][j], wv, a2);
            a3 = fmaf(hb[r0 + 3][j], wv, a3);
        }
        const float bb = fb2[d];
        yb[r0 + 0][d] = a0 + bb + xr[r0 + 0][d];
        yb[r0 + 1][d] = a1 + bb + xr[r0 + 1][d];
        yb[r0 + 2][d] = a2 + bb + xr[r0 + 2][d];
        yb[r0 + 3][d] = a3 + bb + xr[r0 + 3][d];
    }
    __syncthreads();

    // LN per row: wave w handles rows 2w, 2w+1
    const int wave = tid >> 6, lane = tid & 63;
    for (int rr = 0; rr < 2; ++rr) {
        const int r = wave * 2 + rr;
        const float y0 = yb[r][lane], y1 = yb[r][lane + 64];
        float sm = y0 + y1;
        #pragma unroll
        for (int off = 32; off; off >>= 1) sm += __shfl_xor(sm, off);
        const float mean = sm * (1.0f / D_);
        const float d0 = y0 - mean, d1 = y1 - mean;
        float sv = fmaf(d0, d0, d1 * d1);
        #pragma unroll
        for (int off = 32; off; off >>= 1) sv += __shfl_xor(sv, off);
        const float rcp = rsqrtf(sv * (1.0f / D_) + 1e-5f);
        xout[(row0 + r) * D_ + lane]      = d0 * rcp * g[lane] + bta[lane];
        xout[(row0 + r) * D_ + lane + 64] = d1 * rcp * g[lane + 64] + bta[lane + 64];
    }
}

// =======================================================================
// Final projection: out[b,q,h] = x[b,T-1,:] . proj_w[q,:,h] + proj_b[q,h]
// =======================================================================
__global__ __launch_bounds__(576) void proj_kernel(
    const float* __restrict__ x, const float* __restrict__ pw,
    const float* __restrict__ pb, float* __restrict__ out)
{
    const int tid = threadIdx.x;
    if (tid >= NB_ * NQ_ * HOR_) return;
    const int b = tid / (NQ_ * HOR_);
    const int rem = tid - b * (NQ_ * HOR_);
    const int qq = rem / HOR_, hh = rem - qq * HOR_;
    const float* xl = x + ((long)b * TT_ + (TT_ - 1)) * D_;
    float s = pb[qq * HOR_ + hh];
    for (int d = 0; d < D_; ++d)
        s = fmaf(xl[d], pw[((long)qq * D_ + d) * HOR_ + hh], s);
    out[tid] = s;
}

} // namespace

extern "C" void kernel_launch(void* const* d_in, const int* in_sizes, int n_in,
                              void* d_out, int out_size, void* d_ws, size_t ws_size,
                              hipStream_t stream) {
    (void)in_sizes; (void)n_in; (void)out_size; (void)ws_size;

    const float* x_cond = (const float*)d_in[0];
    const float* x_pred = (const float*)d_in[1];
    const float* cw_c   = (const float*)d_in[2];
    const float* cb_c   = (const float*)d_in[3];
    const float* sw_c   = (const float*)d_in[4];
    const float* sb_c   = (const float*)d_in[5];
    const float* cw_p   = (const float*)d_in[6];
    const float* cb_p   = (const float*)d_in[7];
    const float* sw_p   = (const float*)d_in[8];
    const float* sb_p   = (const float*)d_in[9];
    const float* Wq     = (const float*)d_in[10];
    const float* bq     = (const float*)d_in[11];
    const float* Wk     = (const float*)d_in[12];
    const float* bk     = (const float*)d_in[13];
    const float* Wv     = (const float*)d_in[14];
    const float* bv     = (const float*)d_in[15];
    const float* Wo     = (const float*)d_in[16];
    const float* bo     = (const float*)d_in[17];
    const float* ln1g   = (const float*)d_in[18];
    const float* ln1b   = (const float*)d_in[19];
    const float* fw1    = (const float*)d_in[20];
    const float* fb1    = (const float*)d_in[21];
    const float* fw2    = (const float*)d_in[22];
    const float* fb2    = (const float*)d_in[23];
    const float* ln2g   = (const float*)d_in[24];
    const float* ln2b   = (const float*)d_in[25];
    const float* pw     = (const float*)d_in[26];
    const float* pb     = (const float*)d_in[27];

    float* outp = (float*)d_out;
    float* ws   = (float*)d_ws;
    float* xA  = ws + WS_XA;
    float* xB  = ws + WS_XB;
    float* qb  = ws + WS_Q;
    float* kb  = ws + WS_K;
    float* vcb = ws + WS_VC;
    float* wvc = ws + WS_WVC;
    float* bvc = ws + WS_BVC;

    // selectors -> x rows [cond: 0..1023, pred: 1024..1535] and v_* outputs
    selector_kernel<8><<<NB_ * TC_, 128, 0, stream>>>(
        x_cond, cw_c, cb_c, sw_c, sb_c, outp + OFF_VC, xA, TC_, 0);
    selector_kernel<4><<<NB_ * TP_, 128, 0, stream>>>(
        x_pred, cw_p, cb_p, sw_p, sb_p, outp + OFF_VP, xA, TP_, TC_);

    for (int l = 0; l < L_; ++l) {
        prep_wvc_kernel<<<1, 256, 0, stream>>>(
            Wv + (long)l * D_ * D_, bv + l * D_, wvc, bvc);
        qkv_kernel<<<NB_ * TT_, 128, 0, stream>>>(
            xA, Wq + (long)l * D_ * D_, bq + l * D_,
            Wk + (long)l * D_ * D_, bk + l * D_, wvc, bvc, qb, kb, vcb);
        attn_kernel<<<NB_ * TT_, 256, 0, stream>>>(
            qb, kb, vcb, xA, xB,
            Wo + (long)l * DK_ * D_, bo + l * D_,
            ln1g + l * D_, ln1b + l * D_,
            outp + OFF_LOGS + (long)l * NB_ * TT_ * TT_);
        ffn_kernel<<<NB_ * TT_ / 8, 256, 0, stream>>>(
            xB, xA, fw1 + (long)l * D_ * DFF_, fb1 + l * DFF_,
            fw2 + (long)l * DFF_ * D_, fb2 + l * D_,
            ln2g + l * D_, ln2b + l * D_);
    }

    proj_kernel<<<1, 576, 0, stream>>>(xA, pw, pb, outp);
}